// Round 22
// baseline (2215.230 us; speedup 1.0000x reference)
//
#include <hip/hip_runtime.h>
#include <stdint.h>

#define NB 8
#define NPT 16384
#define NM 1024
#define NK 32

// ws layout (float element offsets)
#define WS_W0T 0                    // 67*64 = 4288   W0t[c][o] = W0[o][c]*s0[o]
#define WS_B0  (WS_W0T + 4288)      // 64             b0*s0+t0
#define WS_W1T (WS_B0 + 64)         // 64*128 = 8192
#define WS_B1  (WS_W1T + 8192)      // 128
#define WS_W2T (WS_B1 + 128)        // 128*256 = 32768
#define WS_B2  (WS_W2T + 32768)     // 256
#define WS_IDX (WS_B2 + 256)        // 8192 ints (FPS indices)
#define WS_NXYZ (WS_IDX + 8192)     // 8*1024*3 = 24576 floats
#define WS_BALL (WS_NXYZ + 24576)   // 8*1024*32 = 262144 ints

// out layout (float element offsets)
#define OUT_XYZ 0
#define OUT_FEAT 24576
#define OUT_IDX (24576 + 2097152)

// ---------------- weight prep: transpose + fold BN scale ----------------
__global__ void prep_weights(const float* __restrict__ W0, const float* __restrict__ b0,
                             const float* __restrict__ s0, const float* __restrict__ t0,
                             const float* __restrict__ W1, const float* __restrict__ b1,
                             const float* __restrict__ s1, const float* __restrict__ t1,
                             const float* __restrict__ W2, const float* __restrict__ b2,
                             const float* __restrict__ s2, const float* __restrict__ t2,
                             float* __restrict__ ws) {
    int id = blockIdx.x * 256 + threadIdx.x;
    if (id < 4288) { int c = id >> 6, o = id & 63;  ws[WS_W0T + id] = W0[o * 67 + c] * s0[o]; return; }
    id -= 4288;
    if (id < 64)   { ws[WS_B0 + id] = fmaf(b0[id], s0[id], t0[id]); return; }
    id -= 64;
    if (id < 8192) { int c = id >> 7, o = id & 127; ws[WS_W1T + id] = W1[o * 64 + c] * s1[o]; return; }
    id -= 8192;
    if (id < 128)  { ws[WS_B1 + id] = fmaf(b1[id], s1[id], t1[id]); return; }
    id -= 128;
    if (id < 32768){ int c = id >> 8, o = id & 255; ws[WS_W2T + id] = W2[o * 128 + c] * s2[o]; return; }
    id -= 32768;
    if (id < 256)  { ws[WS_B2 + id] = fmaf(b2[id], s2[id], t2[id]); return; }
}

#define FOREACH16(M) M(0) M(1) M(2) M(3) M(4) M(5) M(6) M(7) \
                     M(8) M(9) M(10) M(11) M(12) M(13) M(14) M(15)

// DPP u32-max step (dpp_ctrl must be an IMMEDIATE -> template param).
template <int CTRL>
__device__ __forceinline__ uint32_t dpp_max_step(uint32_t v) {
    uint32_t o = (uint32_t)__builtin_amdgcn_update_dpp((int)v, (int)v, CTRL, 0xf, 0xf, false);
    return v > o ? v : o;
}
__device__ __forceinline__ uint32_t wave_max_u32(uint32_t v) {
    v = dpp_max_step<0x111>(v);
    v = dpp_max_step<0x112>(v);
    v = dpp_max_step<0x114>(v);
    v = dpp_max_step<0x118>(v);
    v = dpp_max_step<0x142>(v);
    v = dpp_max_step<0x143>(v);
    return v;
}
__device__ __forceinline__ uint32_t row_max_u32(uint32_t v) {
    v = dpp_max_step<0x111>(v);
    v = dpp_max_step<0x112>(v);
    v = dpp_max_step<0x114>(v);
    v = dpp_max_step<0x118>(v);
    return v;
}

// ---------------- farthest point sampling v10 (R18: 1760us, 97% of the 8-CU
// issue ceiling -- structural roofline; unchanged) ----------------
__global__ __attribute__((amdgpu_flat_work_group_size(1024, 1024)))
void fps10_kernel(const float* __restrict__ xyz, int* __restrict__ out_idx) {
    __shared__ float2 pxy[NPT];          // 128 KB
    __shared__ uint2 s_red[2][16];       // {lo=~idx, hi=dist bits} per wave
    int b = blockIdx.x, t = threadIdx.x;
    const float* __restrict__ Xp = xyz + (size_t)b * NPT * 3;

#define DECL_PT(j) float pz##j, dd##j;
    FOREACH16(DECL_PT)
#undef DECL_PT

#define LOAD_PT(j) { int p = t + (j) * 1024; \
        float x = Xp[p * 3 + 0], y = Xp[p * 3 + 1]; \
        pz##j = Xp[p * 3 + 2]; \
        pxy[p] = make_float2(x, y); \
        dd##j = 1e10f; }
    FOREACH16(LOAD_PT)
#undef LOAD_PT
    __syncthreads();

    int farthest = 0;
    float cx = Xp[0], cy = Xp[1], cz = Xp[2];
    int lane = t & 63, w = t >> 6;
    for (int it = 0; it < NM; ++it) {
        if (t == 0) out_idx[b * NM + it] = farthest;
        float best = -1.0f; int bi = 0;
#define STEP_PT(j) { \
        float2 q = pxy[t + (j) * 1024]; \
        float dx = __fsub_rn(q.x, cx); \
        float dy = __fsub_rn(q.y, cy); \
        float dz = __fsub_rn(pz##j, cz); \
        float d  = __fadd_rn(__fadd_rn(__fmul_rn(dx, dx), __fmul_rn(dy, dy)), __fmul_rn(dz, dz)); \
        dd##j = fminf(dd##j, d); \
        if (dd##j > best) { best = dd##j; bi = t + (j) * 1024; } }
        FOREACH16(STEP_PT)
#undef STEP_PT
        uint32_t bbits = __float_as_uint(best);
        uint32_t wmax = __builtin_amdgcn_readlane(wave_max_u32(bbits), 63);
        uint32_t cand = (bbits == wmax) ? ~(uint32_t)bi : 0u;
        uint32_t cwin = __builtin_amdgcn_readlane(wave_max_u32(cand), 63);
        if (lane == 0) s_red[it & 1][w] = make_uint2(cwin, wmax);
        __syncthreads();
        uint2 e = s_red[it & 1][lane & 15];
        uint32_t hmax = __builtin_amdgcn_readlane(row_max_u32(e.y), 15);
        uint32_t c2 = (e.y == hmax) ? e.x : 0u;
        uint32_t c2w = __builtin_amdgcn_readlane(row_max_u32(c2), 15);
        int widx = (int)(~c2w);
        farthest = widx;
        float2 cc = pxy[widx];
        cx = cc.x; cy = cc.y;
        cz = Xp[(size_t)widx * 3 + 2];
    }
}

// ---------------- gather new_xyz + emit indices as float ----------------
__global__ void gather_newxyz(const float* __restrict__ xyz, const int* __restrict__ idx_ws,
                              float* __restrict__ nxyz_ws, float* __restrict__ out_xyz,
                              float* __restrict__ out_idx_f) {
    int id = blockIdx.x * 256 + threadIdx.x;
    if (id >= NB * NM) return;
    int b = id / NM;
    int p = idx_ws[id];
    const float* Xp = xyz + ((size_t)b * NPT + p) * 3;
    float x = Xp[0], y = Xp[1], z = Xp[2];
    nxyz_ws[id * 3 + 0] = x; nxyz_ws[id * 3 + 1] = y; nxyz_ws[id * 3 + 2] = z;
    out_xyz[id * 3 + 0] = x; out_xyz[id * 3 + 1] = y; out_xyz[id * 3 + 2] = z;
    out_idx_f[id] = (float)p;
}

// ---------------- ball query v4: SIXTEEN centers per block ----------------
// Center-sharing trend: 1->4 ctr = -125us (R20), 4->8 = ~-60us (R21). R22: 16
// centers/block -> point loads /2 again (512 blocks x 196KB ~ 100MB L2 reads);
// per-center VALU doubles (~68us chip-total, still below the load savings).
// Register audit: 48 center floats + 16 u64 masks ~ 80 + temps; watch VGPR_Count
// for the known ~128 spill cliff. Per-center math/scan/emit byte-identical.
__global__ __launch_bounds__(256) void ball_query_kernel(const float* __restrict__ xyz,
                                                         const float* __restrict__ nxyz,
                                                         int* __restrict__ ball) {
    int blk = blockIdx.x;                  // 0..511
    int b = blk >> 6;                      // 64 blocks per batch
    int m0 = (blk & 63) * 16;              // centers m0..m0+15
    int t = threadIdx.x;
    const float* Xp = xyz + (size_t)b * NPT * 3;
    float cx[16], cy[16], cz[16];
#pragma unroll
    for (int q2 = 0; q2 < 16; q2++) {
        size_t nb2 = ((size_t)b * NM + m0 + q2) * 3;
        cx[q2] = nxyz[nb2 + 0]; cy[q2] = nxyz[nb2 + 1]; cz[q2] = nxyz[nb2 + 2];
    }
    const float r2 = (float)(0.4 * 0.4);
    uint64_t mask[16] = {0, 0, 0, 0, 0, 0, 0, 0, 0, 0, 0, 0, 0, 0, 0, 0};
    int base = t * 64;
    const float4* q = (const float4*)(Xp + (size_t)base * 3);
#pragma unroll 2
    for (int c = 0; c < 16; c++) {
        float4 A = q[c * 3 + 0], B = q[c * 3 + 1], C = q[c * 3 + 2];
        float xs[4] = {A.x, A.w, B.z, C.y};
        float ys[4] = {A.y, B.x, B.w, C.z};
        float zs[4] = {A.z, B.y, C.x, C.w};
#pragma unroll
        for (int u = 0; u < 4; u++) {
#pragma unroll
            for (int ctr = 0; ctr < 16; ctr++) {
                float dx = __fsub_rn(xs[u], cx[ctr]);
                float dy = __fsub_rn(ys[u], cy[ctr]);
                float dz = __fsub_rn(zs[u], cz[ctr]);
                float d2 = __fadd_rn(__fadd_rn(__fmul_rn(dx, dx), __fmul_rn(dy, dy)), __fmul_rn(dz, dz));
                if (d2 <= r2) mask[ctr] |= (1ull << (c * 4 + u));
            }
        }
    }
    __shared__ int s_wsum[4];
    __shared__ int s_hit[32];
    int w = t >> 6;
#pragma unroll
    for (int ctr = 0; ctr < 16; ctr++) {
        uint64_t mk = mask[ctr];
        int cnt = __popcll(mk);
        int scan = cnt;                    // wave inclusive scan
        for (int off = 1; off < 64; off <<= 1) {
            int nv = __shfl_up(scan, off);
            if ((t & 63) >= off) scan += nv;
        }
        if ((t & 63) == 63) s_wsum[w] = scan;
        __syncthreads();
        int woff = 0;
        for (int i = 0; i < 4; i++) if (i < w) woff += s_wsum[i];
        int excl = woff + scan - cnt;      // exclusive prefix in point-index order
        uint64_t mm = mk; int pos = excl;
        while (mm && pos < 32) {
            int j = __ffsll((long long)mm) - 1;
            s_hit[pos] = base + j;
            pos++;
            mm &= mm - 1;
        }
        __syncthreads();
        int total = s_wsum[0] + s_wsum[1] + s_wsum[2] + s_wsum[3];
        if (t < 32) {
            int first = s_hit[0];          // total >= 1 (center itself at d2=0)
            ball[((size_t)b * NM + m0 + ctr) * NK + t] = (t < total) ? s_hit[t] : first;
        }
        __syncthreads();                   // s_hit/s_wsum reused next ctr
    }
}

// ---------------- fused group + 3xMLP + max over K (R21 version: union buffer
// incl. h1 -> 34KB LDS, 4 blocks/CU; scalar weight path via readfirstlane) ----------------
__global__ __attribute__((amdgpu_flat_work_group_size(256, 256), amdgpu_waves_per_eu(4, 4)))
void fused_mlp_kernel(const float* __restrict__ xyz,
                      const float* __restrict__ feats,
                      const float* __restrict__ ws_f,
                      const int* __restrict__ ball,
                      const float* __restrict__ nxyz,
                      float* __restrict__ out_feat) {
    int blk = blockIdx.x;
    int b = blk >> 9;
    int m0 = (blk & 511) * 2;
    int t = threadIdx.x;
    int k = t & 31, g = t >> 5;            // staging mapping
    int lane = t & 63, wv = t >> 6;        // layer mapping: wave wv, lane = (ctr,k2)
    int ctr = lane >> 5, k2 = lane & 31;
    __shared__ float u[2][131][32];        // rows 0..66: Xs -> h2 rows 0..127; rows 67..130: h1
    __shared__ int sidx[2][32];
    const float* W0t = ws_f + WS_W0T; const float* b0f = ws_f + WS_B0;
    const float* W1t = ws_f + WS_W1T; const float* b1f = ws_f + WS_B1;
    const float* W2t = ws_f + WS_W2T; const float* b2f = ws_f + WS_B2;

    if (t < 64) {
        int c2 = t >> 5;
        sidx[c2][t & 31] = ball[((size_t)b * NM + m0 + c2) * NK + (t & 31)];
    }
    __syncthreads();

    const float* Xp = xyz + (size_t)b * NPT * 3;
    if (g < 6) {
        int c2 = g / 3, dim = g % 3;
        float cc = nxyz[((size_t)b * NM + m0 + c2) * 3 + dim];
        u[c2][dim][k] = Xp[sidx[c2][k] * 3 + dim] - cc;
    }
    const float* Fp = feats + (size_t)b * 64 * NPT;
#pragma unroll
    for (int i = 0; i < 8; i++) {
        int c = g + 8 * i;
        u[0][3 + c][k] = Fp[(size_t)c * NPT + sidx[0][k]];
        u[1][3 + c][k] = Fp[(size_t)c * NPT + sidx[1][k]];
    }
    __syncthreads();

    // layer 1: 67 -> 64. Wave wv owns outputs [wv*16, +16); h1 goes to u rows 67+o.
    {
        int ob = __builtin_amdgcn_readfirstlane(wv * 16);   // SGPR output base
        float acc[16];
#pragma unroll
        for (int i = 0; i < 16; i++) acc[i] = b0f[ob + i];
#pragma unroll 4
        for (int c = 0; c < 67; c++) {
            float xv = u[ctr][c][k2];
            const float* wr = W0t + c * 64 + ob;            // wave-uniform -> s_load
#pragma unroll
            for (int i = 0; i < 16; i++) acc[i] = fmaf(wr[i], xv, acc[i]);
        }
#pragma unroll
        for (int i = 0; i < 16; i++) u[ctr][67 + ob + i][k2] = fmaxf(acc[i], 0.0f);
    }
    __syncthreads();

    // layer 2: 64 -> 128 in 2 passes. Reads h1 (rows 67..130), writes h2 (rows 0..127).
#pragma unroll
    for (int p = 0; p < 2; p++) {
        int ob = __builtin_amdgcn_readfirstlane(wv * 16 + p * 64);
        float acc[16];
#pragma unroll
        for (int i = 0; i < 16; i++) acc[i] = b1f[ob + i];
#pragma unroll 4
        for (int c = 0; c < 64; c++) {
            float xv = u[ctr][67 + c][k2];
            const float* wr = W1t + c * 128 + ob;           // wave-uniform -> s_load
#pragma unroll
            for (int i = 0; i < 16; i++) acc[i] = fmaf(wr[i], xv, acc[i]);
        }
        __syncthreads();   // all reads of h1/Xs rows done before this pass overwrites
#pragma unroll
        for (int i = 0; i < 16; i++) u[ctr][ob + i][k2] = fmaxf(acc[i], 0.0f);
    }
    __syncthreads();

    // layer 3: 128 -> 256 in 4 passes + max over k2 (32-lane group reduce).
#pragma unroll
    for (int p = 0; p < 4; p++) {
        int ob = __builtin_amdgcn_readfirstlane(wv * 16 + p * 64);
        float acc[16];
#pragma unroll
        for (int i = 0; i < 16; i++) acc[i] = b2f[ob + i];
#pragma unroll 4
        for (int c = 0; c < 128; c++) {
            float xv = u[ctr][c][k2];
            const float* wr = W2t + c * 256 + ob;           // wave-uniform -> s_load
#pragma unroll
            for (int i = 0; i < 16; i++) acc[i] = fmaf(wr[i], xv, acc[i]);
        }
#pragma unroll
        for (int i = 0; i < 16; i++) {
            float v = fmaxf(acc[i], 0.0f);
#pragma unroll
            for (int off = 16; off >= 1; off >>= 1) v = fmaxf(v, __shfl_xor(v, off));
            if (k2 == 0) {
                size_t o = (size_t)b * 256 + ob + i;
                out_feat[o * NM + m0 + ctr] = v;
            }
        }
    }
}

extern "C" void kernel_launch(void* const* d_in, const int* in_sizes, int n_in,
                              void* d_out, int out_size, void* d_ws, size_t ws_size,
                              hipStream_t stream) {
    const float* xyz   = (const float*)d_in[0];
    const float* feats = (const float*)d_in[1];
    const float* W0 = (const float*)d_in[2];  const float* b0 = (const float*)d_in[3];
    const float* s0 = (const float*)d_in[4];  const float* t0 = (const float*)d_in[5];
    const float* W1 = (const float*)d_in[6];  const float* b1 = (const float*)d_in[7];
    const float* s1 = (const float*)d_in[8];  const float* t1 = (const float*)d_in[9];
    const float* W2 = (const float*)d_in[10]; const float* b2 = (const float*)d_in[11];
    const float* s2 = (const float*)d_in[12]; const float* t2 = (const float*)d_in[13];

    float* ws_f = (float*)d_ws;
    int*   idx_ws  = (int*)(ws_f + WS_IDX);
    float* nxyz_ws = ws_f + WS_NXYZ;
    int*   ball_ws = (int*)(ws_f + WS_BALL);

    float* out_f = (float*)d_out;
    float* out_xyz  = out_f + OUT_XYZ;
    float* out_feat = out_f + OUT_FEAT;
    float* out_idxf = out_f + OUT_IDX;

    prep_weights<<<179, 256, 0, stream>>>(W0, b0, s0, t0, W1, b1, s1, t1, W2, b2, s2, t2, ws_f);
    fps10_kernel<<<NB, 1024, 0, stream>>>(xyz, idx_ws);
    gather_newxyz<<<32, 256, 0, stream>>>(xyz, idx_ws, nxyz_ws, out_xyz, out_idxf);
    ball_query_kernel<<<NB * NM / 16, 256, 0, stream>>>(xyz, nxyz_ws, ball_ws);
    fused_mlp_kernel<<<NB * NM / 2, 256, 0, stream>>>(xyz, feats, ws_f, ball_ws, nxyz_ws, out_feat);
}